// Round 26
// baseline (293.931 us; speedup 1.0000x reference)
//
#include <hip/hip_runtime.h>
#include <hip/hip_bf16.h>

using short8 = __attribute__((ext_vector_type(8))) short;
using f32x4  = __attribute__((ext_vector_type(4))) float;

#define DEV __device__ __forceinline__

DEV unsigned short f2b(float f) {
  union { float f; unsigned u; } cv; cv.f = f;
  unsigned r = (cv.u + 0x7fffu + ((cv.u >> 16) & 1u)) >> 16;
  return (unsigned short)r;
}
DEV float b2f(unsigned short u) {
  union { unsigned u; float f; } cv; cv.u = ((unsigned)u) << 16; return cv.f;
}
// tanh-form GELU via exp2 (max |diff| vs exact-erf gelu ~3e-4)
DEV float gelu_t(float x) {
  float x2 = x * x;
  float t = __builtin_fmaf(0.044715f * x2, x, x);
  float y = 2.0f * 0.7978845608028654f * t;
  float e = __builtin_amdgcn_exp2f(y * 1.4426950408889634f);
  float th = 1.0f - 2.0f / (e + 1.0f);
  return 0.5f * x * (1.0f + th);
}

typedef const __attribute__((address_space(1))) unsigned int* gp1;
typedef __attribute__((address_space(3))) unsigned int* lp3;
DEV void gl16(const void* g, void* l) {
  __builtin_amdgcn_global_load_lds((gp1)g, (lp3)l, 16, 0, 0);
}

// ---- fused pre-pass: 4 weight transposes + LN1, one launch ----
__global__ void k_pre(const float* __restrict__ s0, unsigned short* __restrict__ d0,
                      const float* __restrict__ s1, unsigned short* __restrict__ d1,
                      const float* __restrict__ s2, unsigned short* __restrict__ d2,
                      const float* __restrict__ s3, unsigned short* __restrict__ d3,
                      const float* __restrict__ x, const float* __restrict__ g1,
                      const float* __restrict__ b1, unsigned short* __restrict__ y) {
  __shared__ float tile[32][33];
  __shared__ float ps[8];
  int id = blockIdx.x;
  int tx = threadIdx.x, ty = threadIdx.y;
  if (id >= 12288) {
    int row = id - 12288;
    int tid = ty * 32 + tx;
    float4 v = reinterpret_cast<const float4*>(x + (size_t)row * 1024)[tid];
    float s  = v.x + v.y + v.z + v.w;
    float s2 = v.x * v.x + v.y * v.y + v.z * v.z + v.w * v.w;
#pragma unroll
    for (int m = 1; m < 64; m <<= 1) { s += __shfl_xor(s, m); s2 += __shfl_xor(s2, m); }
    int w = tid >> 6;
    if ((tid & 63) == 0) { ps[w] = s; ps[4 + w] = s2; }
    __syncthreads();
    s  = ps[0] + ps[1] + ps[2] + ps[3];
    s2 = ps[4] + ps[5] + ps[6] + ps[7];
    float mu   = s * (1.0f / 1024.0f);
    float var  = fmaxf(s2 * (1.0f / 1024.0f) - mu * mu, 0.f);
    float rstd = rsqrtf(var + 1e-5f);
    float4 gv = reinterpret_cast<const float4*>(g1)[tid];
    float4 bv = reinterpret_cast<const float4*>(b1)[tid];
    ushort4 o;
    o.x = f2b((v.x - mu) * rstd * gv.x + bv.x);
    o.y = f2b((v.y - mu) * rstd * gv.y + bv.y);
    o.z = f2b((v.z - mu) * rstd * gv.z + bv.z);
    o.w = f2b((v.w - mu) * rstd * gv.w + bv.w);
    reinterpret_cast<ushort4*>(y + (size_t)row * 1024)[tid] = o;
    return;
  }
  const float* src; unsigned short* dst; int K, N, nx;
  if (id < 3072)      { src = s0; dst = d0; K = 1024; N = 3072; nx = 96; }
  else if (id < 4096) { id -= 3072; src = s1; dst = d1; K = 1024; N = 1024; nx = 32; }
  else if (id < 8192) { id -= 4096; src = s2; dst = d2; K = 1024; N = 4096; nx = 128; }
  else                { id -= 8192; src = s3; dst = d3; K = 4096; N = 1024; nx = 32; }
  int n0 = (id % nx) * 32, k0 = (id / nx) * 32;
#pragma unroll
  for (int j = 0; j < 4; ++j)
    tile[ty + j * 8][tx] = src[(size_t)(k0 + ty + j * 8) * N + (n0 + tx)];
  __syncthreads();
#pragma unroll
  for (int j = 0; j < 4; ++j)
    dst[(size_t)(n0 + ty + j * 8) * K + (k0 + tx)] = f2b(tile[tx][ty + j * 8]);
}

// ---- LayerNorm (bf16 in): [rows][1024] bf16 -> bf16 out ----
__global__ __launch_bounds__(256) void k_lnb(const unsigned short* __restrict__ x,
                                             const float* __restrict__ g,
                                             const float* __restrict__ b,
                                             unsigned short* __restrict__ y) {
  int row = blockIdx.x, tid = threadIdx.x;
  ushort4 u = reinterpret_cast<const ushort4*>(x + (size_t)row * 1024)[tid];
  float vx = b2f(u.x), vy = b2f(u.y), vz = b2f(u.z), vw = b2f(u.w);
  float s  = vx + vy + vz + vw;
  float s2 = vx * vx + vy * vy + vz * vz + vw * vw;
#pragma unroll
  for (int m = 1; m < 64; m <<= 1) { s += __shfl_xor(s, m); s2 += __shfl_xor(s2, m); }
  __shared__ float ps[8];
  int w = tid >> 6;
  if ((tid & 63) == 0) { ps[w] = s; ps[4 + w] = s2; }
  __syncthreads();
  s  = ps[0] + ps[1] + ps[2] + ps[3];
  s2 = ps[4] + ps[5] + ps[6] + ps[7];
  float mu   = s * (1.0f / 1024.0f);
  float var  = fmaxf(s2 * (1.0f / 1024.0f) - mu * mu, 0.f);
  float rstd = rsqrtf(var + 1e-5f);
  float4 gv = reinterpret_cast<const float4*>(g)[tid];
  float4 bv = reinterpret_cast<const float4*>(b)[tid];
  ushort4 o;
  o.x = f2b((vx - mu) * rstd * gv.x + bv.x);
  o.y = f2b((vy - mu) * rstd * gv.y + bv.y);
  o.z = f2b((vz - mu) * rstd * gv.z + bv.z);
  o.w = f2b((vw - mu) * rstd * gv.w + bv.w);
  reinterpret_cast<ushort4*>(y + (size_t)row * 1024)[tid] = o;
}

enum { EPI_QKV = 0, EPI_RESID = 1, EPI_GELU = 2 };

// ---- GEMM 256x256: 16 waves (4Mx4N, 64x64/wave), BK=64, dbuf, counted vmcnt(4) ----
template <int EPI>
__global__ __launch_bounds__(1024, 1) void k_gemm256(
    const unsigned short* __restrict__ A, const unsigned short* __restrict__ BT,
    const float* __restrict__ bias, int M, int N, int K,
    unsigned short* __restrict__ outb,
    unsigned short* __restrict__ qb, unsigned short* __restrict__ kb,
    unsigned short* __restrict__ vb) {
  __shared__ __align__(16) unsigned short Abuf[2][256][64];
  __shared__ __align__(16) unsigned short Bbuf[2][256][64];
  int nx = gridDim.x;
  int w0 = blockIdx.y * nx + blockIdx.x;
  int s = w0 & 7, r = w0 >> 3;
  int bx, by;
  if (nx == 16) {
    int st = r >> 4, p = r & 15;
    bx = (s & 3) * 4 + (p & 3);
    by = (s >> 2) * 8 + st * 4 + (p >> 2);
  } else {
    int byl = r / 6, bxl = r % 6;
    bx = (s & 1) * 6 + bxl;
    by = (s >> 1) * 4 + byl;
  }
  int m0 = by * 256, n0 = bx * 256;
  int tid = threadIdx.x;
  int lane = tid & 63, wid = tid >> 6;
  int wm = wid >> 2, wn = wid & 3;
  int l15 = lane & 15, g = lane >> 4;
  int swl = l15 & 7;
  int lrow = lane >> 3;
  int lchunk = (lane & 7) ^ lrow;
  const unsigned short* Asrc = A  + (size_t)(m0 + wid * 16 + lrow) * K + lchunk * 8;
  const unsigned short* Bsrc = BT + (size_t)(n0 + wid * 16 + lrow) * K + lchunk * 8;
  auto stage = [&](int buf, int k0) {
#pragma unroll
    for (int i = 0; i < 2; ++i)
      gl16(Asrc + k0 + (size_t)i * 8 * K, &Abuf[buf][wid * 16 + i * 8][0]);
#pragma unroll
    for (int i = 0; i < 2; ++i)
      gl16(Bsrc + k0 + (size_t)i * 8 * K, &Bbuf[buf][wid * 16 + i * 8][0]);
  };
  f32x4 acc[4][4] = {};
  int nt = K >> 6;
  stage(0, 0);
  stage(1, 64);
  asm volatile("s_waitcnt vmcnt(4)" ::: "memory");
  __builtin_amdgcn_sched_barrier(0);
  __builtin_amdgcn_s_barrier();
  int cur = 0;
  for (int t = 0; t < nt; ++t) {
    const unsigned short (*As)[64] = Abuf[cur];
    const unsigned short (*Bs)[64] = Bbuf[cur];
    short8 a0[4], b0[4], a1[4], b1[4];
#pragma unroll
    for (int mi = 0; mi < 4; ++mi)
      a0[mi] = *reinterpret_cast<const short8*>(&As[wm * 64 + mi * 16 + l15][(g ^ swl) * 8]);
#pragma unroll
    for (int ni = 0; ni < 4; ++ni)
      b0[ni] = *reinterpret_cast<const short8*>(&Bs[wn * 64 + ni * 16 + l15][(g ^ swl) * 8]);
    __builtin_amdgcn_s_setprio(1);
#pragma unroll
    for (int mi = 0; mi < 4; ++mi)
#pragma unroll
      for (int ni = 0; ni < 4; ++ni)
        acc[mi][ni] = __builtin_amdgcn_mfma_f32_16x16x32_bf16(a0[mi], b0[ni], acc[mi][ni], 0, 0, 0);
    __builtin_amdgcn_s_setprio(0);
#pragma unroll
    for (int mi = 0; mi < 4; ++mi)
      a1[mi] = *reinterpret_cast<const short8*>(&As[wm * 64 + mi * 16 + l15][((4 + g) ^ swl) * 8]);
#pragma unroll
    for (int ni = 0; ni < 4; ++ni)
      b1[ni] = *reinterpret_cast<const short8*>(&Bs[wn * 64 + ni * 16 + l15][((4 + g) ^ swl) * 8]);
    asm volatile("s_waitcnt lgkmcnt(0)" ::: "memory");
    __builtin_amdgcn_sched_barrier(0);
    __builtin_amdgcn_s_barrier();
    __builtin_amdgcn_sched_barrier(0);
    if (t + 2 < nt) stage(cur, (t + 2) << 6);
    __builtin_amdgcn_s_setprio(1);
#pragma unroll
    for (int mi = 0; mi < 4; ++mi)
#pragma unroll
      for (int ni = 0; ni < 4; ++ni)
        acc[mi][ni] = __builtin_amdgcn_mfma_f32_16x16x32_bf16(a1[mi], b1[ni], acc[mi][ni], 0, 0, 0);
    __builtin_amdgcn_s_setprio(0);
    if (t + 2 < nt) {
      asm volatile("s_waitcnt vmcnt(4)" ::: "memory");
    } else if (t + 1 < nt) {
      asm volatile("s_waitcnt vmcnt(0)" ::: "memory");
    }
    __builtin_amdgcn_sched_barrier(0);
    __builtin_amdgcn_s_barrier();
    cur ^= 1;
  }
#pragma unroll
  for (int mi = 0; mi < 4; ++mi) {
#pragma unroll
    for (int ni = 0; ni < 4; ++ni) {
      int row0 = m0 + wm * 64 + mi * 16 + g * 4;
      int col  = n0 + wn * 64 + ni * 16 + l15;
      float bcol = bias[col];
      if (EPI == EPI_QKV) {
        int which = col >> 10;
        int hc = col & 1023;
        int h = hc >> 6, d = hc & 63;
        int bb = row0 >> 11, ss0 = row0 & 2047;
        if (which == 2) {
          ushort4 pk;
          pk.x = f2b(acc[mi][ni][0] + bcol);
          pk.y = f2b(acc[mi][ni][1] + bcol);
          pk.z = f2b(acc[mi][ni][2] + bcol);
          pk.w = f2b(acc[mi][ni][3] + bcol);
          *reinterpret_cast<ushort4*>(&vb[(((size_t)(bb * 16 + h)) * 64 + d) * 2048 + ss0]) = pk;
        } else {
#pragma unroll
          for (int j = 0; j < 4; ++j) {
            float vv = acc[mi][ni][j] + bcol;
            size_t idx = (((size_t)(bb * 16 + h)) * 2048 + ss0 + j) * 64 + d;
            unsigned short bv_ = f2b(which == 0 ? vv * 0.18033688011112042f : vv);
            if (which == 0) qb[idx] = bv_;
            else            kb[idx] = bv_;
          }
        }
      } else {
#pragma unroll
        for (int j = 0; j < 4; ++j) {
          float vv = acc[mi][ni][j] + bcol;
          outb[(size_t)(row0 + j) * N + col] = f2b(gelu_t(vv));
        }
      }
    }
  }
}

// ---- GEMM 64x128 (MxN), 8 waves (32x32/wave), BK=64, dbuf, counted vmcnt(3) ----
template <int RESB, int OUTB>
__global__ __launch_bounds__(512) void k_gemm512(
    const unsigned short* __restrict__ A, const unsigned short* __restrict__ BT,
    const float* __restrict__ bias, int M, int N, int K,
    float* __restrict__ outf, unsigned short* __restrict__ outw,
    const float* __restrict__ residf, const unsigned short* __restrict__ residb) {
  __shared__ __align__(16) unsigned short Abuf[2][64][64];
  __shared__ __align__(16) unsigned short Bbuf[2][128][64];
  int nx = gridDim.x;
  int w0 = blockIdx.y * nx + blockIdx.x;
  int s = w0 & 7, r = w0 >> 3;
  int bx = (s & 3) * 2 + (r & 1);
  int by = (s >> 2) * 32 + (r >> 1);
  int m0 = by * 64, n0 = bx * 128;
  int tid = threadIdx.x;
  int lane = tid & 63, wid = tid >> 6;
  int wm = wid >> 2, wn = wid & 3;
  int l15 = lane & 15, g = lane >> 4;
  int swl = l15 & 7;
  int lrow = lane >> 3;
  int lchunk = (lane & 7) ^ lrow;
  const unsigned short* Asrc = A  + (size_t)(m0 + wid * 8 + lrow) * K + lchunk * 8;
  const unsigned short* Bsrc = BT + (size_t)(n0 + wid * 16 + lrow) * K + lchunk * 8;
  auto stage = [&](int buf, int k0) {
    gl16(Asrc + k0, &Abuf[buf][wid * 8][0]);
#pragma unroll
    for (int i = 0; i < 2; ++i)
      gl16(Bsrc + k0 + (size_t)i * 8 * K, &Bbuf[buf][wid * 16 + i * 8][0]);
  };
  f32x4 acc[2][2] = {};
  int nt = K >> 6;
  stage(0, 0);
  stage(1, 64);
  asm volatile("s_waitcnt vmcnt(3)" ::: "memory");
  __builtin_amdgcn_sched_barrier(0);
  __builtin_amdgcn_s_barrier();
  int cur = 0;
  for (int t = 0; t < nt; ++t) {
    const unsigned short (*As)[64] = Abuf[cur];
    const unsigned short (*Bs)[64] = Bbuf[cur];
    short8 a0[2], b0[2], a1[2], b1[2];
#pragma unroll
    for (int mi = 0; mi < 2; ++mi)
      a0[mi] = *reinterpret_cast<const short8*>(&As[wm * 32 + mi * 16 + l15][(g ^ swl) * 8]);
#pragma unroll
    for (int ni = 0; ni < 2; ++ni)
      b0[ni] = *reinterpret_cast<const short8*>(&Bs[wn * 32 + ni * 16 + l15][(g ^ swl) * 8]);
    __builtin_amdgcn_s_setprio(1);
#pragma unroll
    for (int mi = 0; mi < 2; ++mi)
#pragma unroll
      for (int ni = 0; ni < 2; ++ni)
        acc[mi][ni] = __builtin_amdgcn_mfma_f32_16x16x32_bf16(a0[mi], b0[ni], acc[mi][ni], 0, 0, 0);
    __builtin_amdgcn_s_setprio(0);
#pragma unroll
    for (int mi = 0; mi < 2; ++mi)
      a1[mi] = *reinterpret_cast<const short8*>(&As[wm * 32 + mi * 16 + l15][((4 + g) ^ swl) * 8]);
#pragma unroll
    for (int ni = 0; ni < 2; ++ni)
      b1[ni] = *reinterpret_cast<const short8*>(&Bs[wn * 32 + ni * 16 + l15][((4 + g) ^ swl) * 8]);
    asm volatile("s_waitcnt lgkmcnt(0)" ::: "memory");
    __builtin_amdgcn_sched_barrier(0);
    __builtin_amdgcn_s_barrier();
    __builtin_amdgcn_sched_barrier(0);
    if (t + 2 < nt) stage(cur, (t + 2) << 6);
    __builtin_amdgcn_s_setprio(1);
#pragma unroll
    for (int mi = 0; mi < 2; ++mi)
#pragma unroll
      for (int ni = 0; ni < 2; ++ni)
        acc[mi][ni] = __builtin_amdgcn_mfma_f32_16x16x32_bf16(a1[mi], b1[ni], acc[mi][ni], 0, 0, 0);
    __builtin_amdgcn_s_setprio(0);
    if (t + 2 < nt) {
      asm volatile("s_waitcnt vmcnt(3)" ::: "memory");
    } else if (t + 1 < nt) {
      asm volatile("s_waitcnt vmcnt(0)" ::: "memory");
    }
    __builtin_amdgcn_sched_barrier(0);
    __builtin_amdgcn_s_barrier();
    cur ^= 1;
  }
#pragma unroll
  for (int mi = 0; mi < 2; ++mi) {
#pragma unroll
    for (int ni = 0; ni < 2; ++ni) {
      int row0 = m0 + wm * 32 + mi * 16 + g * 4;
      int col  = n0 + wn * 32 + ni * 16 + l15;
      float bcol = bias[col];
#pragma unroll
      for (int j = 0; j < 4; ++j) {
        size_t idx = (size_t)(row0 + j) * N + col;
        float rv = RESB ? b2f(residb[idx]) : residf[idx];
        float vv = acc[mi][ni][j] + bcol + rv;
        if (OUTB) outw[idx] = f2b(vv);
        else      outf[idx] = vv;
      }
    }
  }
}

// ---- flash attention: 1-D grid 512, XCD-clustered, KVBLK=128, both-halves ILP ----
// V read DIRECTLY from global (XCD-L2-resident; FETCH=12MB proves it) -- no Vs staging.
__global__ __launch_bounds__(512) void k_attn(
    const unsigned short* __restrict__ qb, const unsigned short* __restrict__ kb,
    const unsigned short* __restrict__ vt, unsigned short* __restrict__ attn_out) {
  __shared__ __align__(16) unsigned short Ks[128][64];
  __shared__ __align__(16) unsigned short Plds[8][2][16][72];
  int id = blockIdx.x;
  int slot = id & 7, step = id >> 3;
  int bh = slot * 4 + (step >> 4);
  int qblk = step & 15;
  int b = bh >> 4, h = bh & 15;
  int tid = threadIdx.x;
  int lane = tid & 63, wid = tid >> 6;
  int l15 = lane & 15, g = lane >> 4;
  int q0 = qblk * 128 + wid * 16;
  const unsigned short* Qb = qb + (size_t)bh * 2048 * 64;
  const unsigned short* Kb = kb + (size_t)bh * 2048 * 64;
  const unsigned short* Vt = vt + (size_t)bh * 64 * 2048;
  short8 qf0 = *reinterpret_cast<const short8*>(&Qb[(size_t)(q0 + l15) * 64 + g * 8]);
  short8 qf1 = *reinterpret_cast<const short8*>(&Qb[(size_t)(q0 + l15) * 64 + 32 + g * 8]);
  short8 vones;
#pragma unroll
  for (int i = 0; i < 8; ++i) vones[i] = (short)0x3F80;
  float mj = 0.0f;
  f32x4 o[4] = {};
  f32x4 lacc = {};
  int kr  = wid * 16 + (lane >> 3);
  int kcn = (lane & 7) ^ (kr & 7);
  int swl = l15 & 7;
  for (int t0 = 0; t0 < 2048; t0 += 128) {
    __syncthreads();
    gl16(Kb + (size_t)(t0 + kr) * 64 + kcn * 8,     &Ks[wid * 16][0]);
    gl16(Kb + (size_t)(t0 + kr + 8) * 64 + kcn * 8, &Ks[wid * 16 + 8][0]);
    __syncthreads();
    f32x4 scv[2][4];
#pragma unroll
    for (int half = 0; half < 2; ++half)
#pragma unroll
      for (int kk = 0; kk < 4; ++kk) {
        short8 kf0 = *reinterpret_cast<const short8*>(&Ks[half * 64 + kk * 16 + l15][(g ^ swl) * 8]);
        short8 kf1 = *reinterpret_cast<const short8*>(&Ks[half * 64 + kk * 16 + l15][((4 + g) ^ swl) * 8]);
        f32x4 z = {};
        z = __builtin_amdgcn_mfma_f32_16x16x32_bf16(kf0, qf0, z, 0, 0, 0);
        scv[half][kk] = __builtin_amdgcn_mfma_f32_16x16x32_bf16(kf1, qf1, z, 0, 0, 0);
      }
    float p[2][16];
#pragma unroll
    for (int half = 0; half < 2; ++half)
#pragma unroll
      for (int kk = 0; kk < 4; ++kk)
#pragma unroll
        for (int j = 0; j < 4; ++j)
          p[half][kk * 4 + j] = __builtin_amdgcn_exp2f(scv[half][kk][j] - mj);
#pragma unroll
    for (int half = 0; half < 2; ++half)
#pragma unroll
      for (int kk = 0; kk < 4; ++kk) {
        unsigned r0, r1;
        asm("v_cvt_pk_bf16_f32 %0, %1, %2" : "=v"(r0) : "v"(p[half][kk * 4 + 0]), "v"(p[half][kk * 4 + 1]));
        asm("v_cvt_pk_bf16_f32 %0, %1, %2" : "=v"(r1) : "v"(p[half][kk * 4 + 2]), "v"(p[half][kk * 4 + 3]));
        unsigned long long w = (unsigned long long)r0 | ((unsigned long long)r1 << 32);
        *reinterpret_cast<unsigned long long*>(&Plds[wid][half][l15][kk * 16 + g * 4]) = w;
      }
    float mx = -1e30f;
#pragma unroll
    for (int half = 0; half < 2; ++half)
#pragma unroll
      for (int kk = 0; kk < 4; ++kk)
#pragma unroll
        for (int j = 0; j < 4; ++j) mx = fmaxf(mx, scv[half][kk][j]);
    mx = fmaxf(mx, __shfl_xor(mx, 16));
    mx = fmaxf(mx, __shfl_xor(mx, 32));
    if (!__all(mx <= mj + 8.0f)) {
      float mnew = fmaxf(mj, mx);
      float ef = __builtin_amdgcn_exp2f(mj - mnew);
      int sb = 20 * g;
      float e0 = __shfl(ef, sb + 0), e1 = __shfl(ef, sb + 1);
      float e2 = __shfl(ef, sb + 2), e3 = __shfl(ef, sb + 3);
#pragma unroll
      for (int ct = 0; ct < 4; ++ct) {
        o[ct][0] *= e0; o[ct][1] *= e1; o[ct][2] *= e2; o[ct][3] *= e3;
      }
      lacc[0] *= e0; lacc[1] *= e1; lacc[2] *= e2; lacc[3] *= e3;
#pragma unroll
      for (int half = 0; half < 2; ++half)
#pragma unroll
        for (int kk = 0; kk < 4; ++kk) {
#pragma unroll
          for (int j = 0; j < 4; ++j)
            p[half][kk * 4 + j] = __builtin_amdgcn_exp2f(scv[half][kk][j] - mnew);
          unsigned r0, r1;
          asm("v_cvt_pk_bf16_f32 %0, %1, %2" : "=v"(r0) : "v"(p[half][kk * 4 + 0]), "v"(p[half][kk * 4 + 1]));
          asm("v_cvt_pk_bf16_f32 %0, %1, %2" : "=v"(r1) : "v"(p[half][kk * 4 + 2]), "v"(p[half][kk * 4 + 3]));
          unsigned long long w = (unsigned long long)r0 | ((unsigned long long)r1 << 32);
          *reinterpret_cast<unsigned long long*>(&Plds[wid][half][l15][kk * 16 + g * 4]) = w;
        }
      mj = mnew;
    }
#pragma unroll
    for (int half = 0; half < 2; ++half) {
      short8 pf0 = *reinterpret_cast<const short8*>(&Plds[wid][half][l15][g * 8]);
      short8 pf1 = *reinterpret_cast<const short8*>(&Plds[wid][half][l15][32 + g * 8]);
      lacc = __builtin_amdgcn_mfma_f32_16x16x32_bf16(pf0, vones, lacc, 0, 0, 0);
      lacc = __builtin_amdgcn_mfma_f32_16x16x32_bf16(pf1, vones, lacc, 0, 0, 0);
#pragma unroll
      for (int ct = 0; ct < 4; ++ct) {
        // V direct from global: row d = ct*16+l15, keys of this half.
        const unsigned short* Vrow = Vt + (size_t)(ct * 16 + l15) * 2048 + t0 + half * 64;
        short8 vf0 = *reinterpret_cast<const short8*>(&Vrow[g * 8]);
        short8 vf1 = *reinterpret_cast<const short8*>(&Vrow[32 + g * 8]);
        o[ct] = __builtin_amdgcn_mfma_f32_16x16x32_bf16(pf0, vf0, o[ct], 0, 0, 0);
        o[ct] = __builtin_amdgcn_mfma_f32_16x16x32_bf16(pf1, vf1, o[ct], 0, 0, 0);
      }
    }
  }
#pragma unroll
  for (int j = 0; j < 4; ++j) {
    float iv = 1.0f / lacc[j];
    size_t t = (size_t)b * 2048 + (q0 + g * 4 + j);
#pragma unroll
    for (int ct = 0; ct < 4; ++ct)
      attn_out[t * 1024 + h * 64 + ct * 16 + l15] = f2b(o[ct][j] * iv);
  }
}

extern "C" void kernel_launch(void* const* d_in, const int* in_sizes, int n_in,
                              void* d_out, int out_size, void* d_ws, size_t ws_size,
                              hipStream_t stream) {
  (void)in_sizes; (void)n_in; (void)out_size; (void)ws_size;
  const float* x      = (const float*)d_in[0];
  const float* ln1_g  = (const float*)d_in[1];
  const float* ln1_b  = (const float*)d_in[2];
  const float* w_qkv  = (const float*)d_in[3];
  const float* b_qkv  = (const float*)d_in[4];
  const float* w_ao   = (const float*)d_in[5];
  const float* b_ao   = (const float*)d_in[6];
  const float* ln2_g  = (const float*)d_in[7];
  const float* ln2_b  = (const float*)d_in[8];
  const float* w_fc   = (const float*)d_in[9];
  const float* b_fc   = (const float*)d_in[10];
  const float* w_proj = (const float*)d_in[11];
  const float* b_proj = (const float*)d_in[12];
  float* out = (float*)d_out;

  char* ws = (char*)d_ws;
  size_t o = 0;
  auto nxt = [&](size_t bytes) { void* p = ws + o; o += (bytes + 255) & ~(size_t)255; return p; };
  unsigned short* wT_qkv  = (unsigned short*)nxt((size_t)3072 * 1024 * 2);
  unsigned short* wT_ao   = (unsigned short*)nxt((size_t)1024 * 1024 * 2);
  unsigned short* wT_fc   = (unsigned short*)nxt((size_t)4096 * 1024 * 2);
  unsigned short* wT_proj = (unsigned short*)nxt((size_t)1024 * 4096 * 2);
  unsigned short* h_ln    = (unsigned short*)nxt((size_t)4096 * 1024 * 2);
  unsigned short* qbuf    = (unsigned short*)nxt((size_t)4096 * 1024 * 2);
  unsigned short* kbuf    = (unsigned short*)nxt((size_t)4096 * 1024 * 2);
  unsigned short* vtb     = (unsigned short*)nxt((size_t)4096 * 1024 * 2);
  unsigned short* attn_o  = (unsigned short*)nxt((size_t)4096 * 1024 * 2);
  unsigned short* out1b   = (unsigned short*)nxt((size_t)4096 * 1024 * 2);
  unsigned short* fc_buf  = qbuf;  // reuse qkv region after attention

  dim3 b32(32, 8, 1);
  k_pre<<<16384, b32, 0, stream>>>(w_qkv, wT_qkv, w_ao, wT_ao, w_fc, wT_fc, w_proj, wT_proj,
                                   x, ln1_g, ln1_b, h_ln);
  k_gemm256<EPI_QKV><<<dim3(12, 16), 1024, 0, stream>>>(h_ln, wT_qkv, b_qkv, 4096, 3072, 1024,
                                                        nullptr, qbuf, kbuf, vtb);
  k_attn<<<512, 512, 0, stream>>>(qbuf, kbuf, vtb, attn_o);
  k_gemm512<0, 1><<<dim3(8, 64), 512, 0, stream>>>(attn_o, wT_ao, b_ao, 4096, 1024, 1024,
                                                   nullptr, out1b, x, nullptr);
  k_lnb<<<4096, 256, 0, stream>>>(out1b, ln2_g, ln2_b, h_ln);
  k_gemm256<EPI_GELU><<<dim3(16, 16), 1024, 0, stream>>>(h_ln, wT_fc, b_fc, 4096, 4096, 1024,
                                                         fc_buf, nullptr, nullptr, nullptr);
  k_gemm512<1, 0><<<dim3(8, 64), 512, 0, stream>>>(fc_buf, wT_proj, b_proj, 4096, 1024, 4096,
                                                   out, nullptr, nullptr, out1b);
}

// Round 27
// 207.418 us; speedup vs baseline: 1.4171x; 1.4171x over previous
//
#include <hip/hip_runtime.h>
#include <hip/hip_bf16.h>

using short8 = __attribute__((ext_vector_type(8))) short;
using f32x4  = __attribute__((ext_vector_type(4))) float;

#define DEV __device__ __forceinline__

DEV unsigned short f2b(float f) {
  union { float f; unsigned u; } cv; cv.f = f;
  unsigned r = (cv.u + 0x7fffu + ((cv.u >> 16) & 1u)) >> 16;
  return (unsigned short)r;
}
DEV float b2f(unsigned short u) {
  union { unsigned u; float f; } cv; cv.u = ((unsigned)u) << 16; return cv.f;
}
// tanh-form GELU via exp2 (max |diff| vs exact-erf gelu ~3e-4)
DEV float gelu_t(float x) {
  float x2 = x * x;
  float t = __builtin_fmaf(0.044715f * x2, x, x);
  float y = 2.0f * 0.7978845608028654f * t;
  float e = __builtin_amdgcn_exp2f(y * 1.4426950408889634f);
  float th = 1.0f - 2.0f / (e + 1.0f);
  return 0.5f * x * (1.0f + th);
}

typedef const __attribute__((address_space(1))) unsigned int* gp1;
typedef __attribute__((address_space(3))) unsigned int* lp3;
DEV void gl16(const void* g, void* l) {
  __builtin_amdgcn_global_load_lds((gp1)g, (lp3)l, 16, 0, 0);
}

// ---- fused pre-pass: 4 weight transposes + LN1, one launch ----
__global__ void k_pre(const float* __restrict__ s0, unsigned short* __restrict__ d0,
                      const float* __restrict__ s1, unsigned short* __restrict__ d1,
                      const float* __restrict__ s2, unsigned short* __restrict__ d2,
                      const float* __restrict__ s3, unsigned short* __restrict__ d3,
                      const float* __restrict__ x, const float* __restrict__ g1,
                      const float* __restrict__ b1, unsigned short* __restrict__ y) {
  __shared__ float tile[32][33];
  __shared__ float ps[8];
  int id = blockIdx.x;
  int tx = threadIdx.x, ty = threadIdx.y;
  if (id >= 12288) {
    int row = id - 12288;
    int tid = ty * 32 + tx;
    float4 v = reinterpret_cast<const float4*>(x + (size_t)row * 1024)[tid];
    float s  = v.x + v.y + v.z + v.w;
    float s2 = v.x * v.x + v.y * v.y + v.z * v.z + v.w * v.w;
#pragma unroll
    for (int m = 1; m < 64; m <<= 1) { s += __shfl_xor(s, m); s2 += __shfl_xor(s2, m); }
    int w = tid >> 6;
    if ((tid & 63) == 0) { ps[w] = s; ps[4 + w] = s2; }
    __syncthreads();
    s  = ps[0] + ps[1] + ps[2] + ps[3];
    s2 = ps[4] + ps[5] + ps[6] + ps[7];
    float mu   = s * (1.0f / 1024.0f);
    float var  = fmaxf(s2 * (1.0f / 1024.0f) - mu * mu, 0.f);
    float rstd = rsqrtf(var + 1e-5f);
    float4 gv = reinterpret_cast<const float4*>(g1)[tid];
    float4 bv = reinterpret_cast<const float4*>(b1)[tid];
    ushort4 o;
    o.x = f2b((v.x - mu) * rstd * gv.x + bv.x);
    o.y = f2b((v.y - mu) * rstd * gv.y + bv.y);
    o.z = f2b((v.z - mu) * rstd * gv.z + bv.z);
    o.w = f2b((v.w - mu) * rstd * gv.w + bv.w);
    reinterpret_cast<ushort4*>(y + (size_t)row * 1024)[tid] = o;
    return;
  }
  const float* src; unsigned short* dst; int K, N, nx;
  if (id < 3072)      { src = s0; dst = d0; K = 1024; N = 3072; nx = 96; }
  else if (id < 4096) { id -= 3072; src = s1; dst = d1; K = 1024; N = 1024; nx = 32; }
  else if (id < 8192) { id -= 4096; src = s2; dst = d2; K = 1024; N = 4096; nx = 128; }
  else                { id -= 8192; src = s3; dst = d3; K = 4096; N = 1024; nx = 32; }
  int n0 = (id % nx) * 32, k0 = (id / nx) * 32;
#pragma unroll
  for (int j = 0; j < 4; ++j)
    tile[ty + j * 8][tx] = src[(size_t)(k0 + ty + j * 8) * N + (n0 + tx)];
  __syncthreads();
#pragma unroll
  for (int j = 0; j < 4; ++j)
    dst[(size_t)(n0 + ty + j * 8) * K + (k0 + tx)] = f2b(tile[tx][ty + j * 8]);
}

// ---- LayerNorm (bf16 in): [rows][1024] bf16 -> bf16 out ----
__global__ __launch_bounds__(256) void k_lnb(const unsigned short* __restrict__ x,
                                             const float* __restrict__ g,
                                             const float* __restrict__ b,
                                             unsigned short* __restrict__ y) {
  int row = blockIdx.x, tid = threadIdx.x;
  ushort4 u = reinterpret_cast<const ushort4*>(x + (size_t)row * 1024)[tid];
  float vx = b2f(u.x), vy = b2f(u.y), vz = b2f(u.z), vw = b2f(u.w);
  float s  = vx + vy + vz + vw;
  float s2 = vx * vx + vy * vy + vz * vz + vw * vw;
#pragma unroll
  for (int m = 1; m < 64; m <<= 1) { s += __shfl_xor(s, m); s2 += __shfl_xor(s2, m); }
  __shared__ float ps[8];
  int w = tid >> 6;
  if ((tid & 63) == 0) { ps[w] = s; ps[4 + w] = s2; }
  __syncthreads();
  s  = ps[0] + ps[1] + ps[2] + ps[3];
  s2 = ps[4] + ps[5] + ps[6] + ps[7];
  float mu   = s * (1.0f / 1024.0f);
  float var  = fmaxf(s2 * (1.0f / 1024.0f) - mu * mu, 0.f);
  float rstd = rsqrtf(var + 1e-5f);
  float4 gv = reinterpret_cast<const float4*>(g)[tid];
  float4 bv = reinterpret_cast<const float4*>(b)[tid];
  ushort4 o;
  o.x = f2b((vx - mu) * rstd * gv.x + bv.x);
  o.y = f2b((vy - mu) * rstd * gv.y + bv.y);
  o.z = f2b((vz - mu) * rstd * gv.z + bv.z);
  o.w = f2b((vw - mu) * rstd * gv.w + bv.w);
  reinterpret_cast<ushort4*>(y + (size_t)row * 1024)[tid] = o;
}

enum { EPI_QKV = 0, EPI_RESID = 1, EPI_GELU = 2 };

// ---- GEMM 256x256: 16 waves (4Mx4N, 64x64/wave), BK=64, dbuf, counted vmcnt(4) ----
template <int EPI>
__global__ __launch_bounds__(1024, 1) void k_gemm256(
    const unsigned short* __restrict__ A, const unsigned short* __restrict__ BT,
    const float* __restrict__ bias, int M, int N, int K,
    unsigned short* __restrict__ outb,
    unsigned short* __restrict__ qb, unsigned short* __restrict__ kb,
    unsigned short* __restrict__ vb) {
  __shared__ __align__(16) unsigned short Abuf[2][256][64];
  __shared__ __align__(16) unsigned short Bbuf[2][256][64];
  int nx = gridDim.x;
  int w0 = blockIdx.y * nx + blockIdx.x;
  int s = w0 & 7, r = w0 >> 3;
  int bx, by;
  if (nx == 16) {
    int st = r >> 4, p = r & 15;
    bx = (s & 3) * 4 + (p & 3);
    by = (s >> 2) * 8 + st * 4 + (p >> 2);
  } else {
    int byl = r / 6, bxl = r % 6;
    bx = (s & 1) * 6 + bxl;
    by = (s >> 1) * 4 + byl;
  }
  int m0 = by * 256, n0 = bx * 256;
  int tid = threadIdx.x;
  int lane = tid & 63, wid = tid >> 6;
  int wm = wid >> 2, wn = wid & 3;
  int l15 = lane & 15, g = lane >> 4;
  int swl = l15 & 7;
  int lrow = lane >> 3;
  int lchunk = (lane & 7) ^ lrow;
  const unsigned short* Asrc = A  + (size_t)(m0 + wid * 16 + lrow) * K + lchunk * 8;
  const unsigned short* Bsrc = BT + (size_t)(n0 + wid * 16 + lrow) * K + lchunk * 8;
  auto stage = [&](int buf, int k0) {
#pragma unroll
    for (int i = 0; i < 2; ++i)
      gl16(Asrc + k0 + (size_t)i * 8 * K, &Abuf[buf][wid * 16 + i * 8][0]);
#pragma unroll
    for (int i = 0; i < 2; ++i)
      gl16(Bsrc + k0 + (size_t)i * 8 * K, &Bbuf[buf][wid * 16 + i * 8][0]);
  };
  f32x4 acc[4][4] = {};
  int nt = K >> 6;
  stage(0, 0);
  stage(1, 64);
  asm volatile("s_waitcnt vmcnt(4)" ::: "memory");
  __builtin_amdgcn_sched_barrier(0);
  __builtin_amdgcn_s_barrier();
  int cur = 0;
  for (int t = 0; t < nt; ++t) {
    const unsigned short (*As)[64] = Abuf[cur];
    const unsigned short (*Bs)[64] = Bbuf[cur];
    short8 a0[4], b0[4], a1[4], b1[4];
#pragma unroll
    for (int mi = 0; mi < 4; ++mi)
      a0[mi] = *reinterpret_cast<const short8*>(&As[wm * 64 + mi * 16 + l15][(g ^ swl) * 8]);
#pragma unroll
    for (int ni = 0; ni < 4; ++ni)
      b0[ni] = *reinterpret_cast<const short8*>(&Bs[wn * 64 + ni * 16 + l15][(g ^ swl) * 8]);
    __builtin_amdgcn_s_setprio(1);
#pragma unroll
    for (int mi = 0; mi < 4; ++mi)
#pragma unroll
      for (int ni = 0; ni < 4; ++ni)
        acc[mi][ni] = __builtin_amdgcn_mfma_f32_16x16x32_bf16(a0[mi], b0[ni], acc[mi][ni], 0, 0, 0);
    __builtin_amdgcn_s_setprio(0);
#pragma unroll
    for (int mi = 0; mi < 4; ++mi)
      a1[mi] = *reinterpret_cast<const short8*>(&As[wm * 64 + mi * 16 + l15][((4 + g) ^ swl) * 8]);
#pragma unroll
    for (int ni = 0; ni < 4; ++ni)
      b1[ni] = *reinterpret_cast<const short8*>(&Bs[wn * 64 + ni * 16 + l15][((4 + g) ^ swl) * 8]);
    asm volatile("s_waitcnt lgkmcnt(0)" ::: "memory");
    __builtin_amdgcn_sched_barrier(0);
    __builtin_amdgcn_s_barrier();
    __builtin_amdgcn_sched_barrier(0);
    if (t + 2 < nt) stage(cur, (t + 2) << 6);
    __builtin_amdgcn_s_setprio(1);
#pragma unroll
    for (int mi = 0; mi < 4; ++mi)
#pragma unroll
      for (int ni = 0; ni < 4; ++ni)
        acc[mi][ni] = __builtin_amdgcn_mfma_f32_16x16x32_bf16(a1[mi], b1[ni], acc[mi][ni], 0, 0, 0);
    __builtin_amdgcn_s_setprio(0);
    if (t + 2 < nt) {
      asm volatile("s_waitcnt vmcnt(4)" ::: "memory");
    } else if (t + 1 < nt) {
      asm volatile("s_waitcnt vmcnt(0)" ::: "memory");
    }
    __builtin_amdgcn_sched_barrier(0);
    __builtin_amdgcn_s_barrier();
    cur ^= 1;
  }
#pragma unroll
  for (int mi = 0; mi < 4; ++mi) {
#pragma unroll
    for (int ni = 0; ni < 4; ++ni) {
      int row0 = m0 + wm * 64 + mi * 16 + g * 4;
      int col  = n0 + wn * 64 + ni * 16 + l15;
      float bcol = bias[col];
      if (EPI == EPI_QKV) {
        int which = col >> 10;
        int hc = col & 1023;
        int h = hc >> 6, d = hc & 63;
        int bb = row0 >> 11, ss0 = row0 & 2047;
        if (which == 2) {
          ushort4 pk;
          pk.x = f2b(acc[mi][ni][0] + bcol);
          pk.y = f2b(acc[mi][ni][1] + bcol);
          pk.z = f2b(acc[mi][ni][2] + bcol);
          pk.w = f2b(acc[mi][ni][3] + bcol);
          *reinterpret_cast<ushort4*>(&vb[(((size_t)(bb * 16 + h)) * 64 + d) * 2048 + ss0]) = pk;
        } else {
#pragma unroll
          for (int j = 0; j < 4; ++j) {
            float vv = acc[mi][ni][j] + bcol;
            size_t idx = (((size_t)(bb * 16 + h)) * 2048 + ss0 + j) * 64 + d;
            unsigned short bv_ = f2b(which == 0 ? vv * 0.18033688011112042f : vv);
            if (which == 0) qb[idx] = bv_;
            else            kb[idx] = bv_;
          }
        }
      } else {
#pragma unroll
        for (int j = 0; j < 4; ++j) {
          float vv = acc[mi][ni][j] + bcol;
          outb[(size_t)(row0 + j) * N + col] = f2b(gelu_t(vv));
        }
      }
    }
  }
}

// ---- GEMM 64x128 (MxN), 8 waves (32x32/wave), BK=64, dbuf, counted vmcnt(3) ----
template <int RESB, int OUTB>
__global__ __launch_bounds__(512) void k_gemm512(
    const unsigned short* __restrict__ A, const unsigned short* __restrict__ BT,
    const float* __restrict__ bias, int M, int N, int K,
    float* __restrict__ outf, unsigned short* __restrict__ outw,
    const float* __restrict__ residf, const unsigned short* __restrict__ residb) {
  __shared__ __align__(16) unsigned short Abuf[2][64][64];
  __shared__ __align__(16) unsigned short Bbuf[2][128][64];
  int nx = gridDim.x;
  int w0 = blockIdx.y * nx + blockIdx.x;
  int s = w0 & 7, r = w0 >> 3;
  int bx = (s & 3) * 2 + (r & 1);
  int by = (s >> 2) * 32 + (r >> 1);
  int m0 = by * 64, n0 = bx * 128;
  int tid = threadIdx.x;
  int lane = tid & 63, wid = tid >> 6;
  int wm = wid >> 2, wn = wid & 3;
  int l15 = lane & 15, g = lane >> 4;
  int swl = l15 & 7;
  int lrow = lane >> 3;
  int lchunk = (lane & 7) ^ lrow;
  const unsigned short* Asrc = A  + (size_t)(m0 + wid * 8 + lrow) * K + lchunk * 8;
  const unsigned short* Bsrc = BT + (size_t)(n0 + wid * 16 + lrow) * K + lchunk * 8;
  auto stage = [&](int buf, int k0) {
    gl16(Asrc + k0, &Abuf[buf][wid * 8][0]);
#pragma unroll
    for (int i = 0; i < 2; ++i)
      gl16(Bsrc + k0 + (size_t)i * 8 * K, &Bbuf[buf][wid * 16 + i * 8][0]);
  };
  f32x4 acc[2][2] = {};
  int nt = K >> 6;
  stage(0, 0);
  stage(1, 64);
  asm volatile("s_waitcnt vmcnt(3)" ::: "memory");
  __builtin_amdgcn_sched_barrier(0);
  __builtin_amdgcn_s_barrier();
  int cur = 0;
  for (int t = 0; t < nt; ++t) {
    const unsigned short (*As)[64] = Abuf[cur];
    const unsigned short (*Bs)[64] = Bbuf[cur];
    short8 a0[2], b0[2], a1[2], b1[2];
#pragma unroll
    for (int mi = 0; mi < 2; ++mi)
      a0[mi] = *reinterpret_cast<const short8*>(&As[wm * 32 + mi * 16 + l15][(g ^ swl) * 8]);
#pragma unroll
    for (int ni = 0; ni < 2; ++ni)
      b0[ni] = *reinterpret_cast<const short8*>(&Bs[wn * 32 + ni * 16 + l15][(g ^ swl) * 8]);
    __builtin_amdgcn_s_setprio(1);
#pragma unroll
    for (int mi = 0; mi < 2; ++mi)
#pragma unroll
      for (int ni = 0; ni < 2; ++ni)
        acc[mi][ni] = __builtin_amdgcn_mfma_f32_16x16x32_bf16(a0[mi], b0[ni], acc[mi][ni], 0, 0, 0);
    __builtin_amdgcn_s_setprio(0);
#pragma unroll
    for (int mi = 0; mi < 2; ++mi)
      a1[mi] = *reinterpret_cast<const short8*>(&As[wm * 32 + mi * 16 + l15][((4 + g) ^ swl) * 8]);
#pragma unroll
    for (int ni = 0; ni < 2; ++ni)
      b1[ni] = *reinterpret_cast<const short8*>(&Bs[wn * 32 + ni * 16 + l15][((4 + g) ^ swl) * 8]);
    asm volatile("s_waitcnt lgkmcnt(0)" ::: "memory");
    __builtin_amdgcn_sched_barrier(0);
    __builtin_amdgcn_s_barrier();
    __builtin_amdgcn_sched_barrier(0);
    if (t + 2 < nt) stage(cur, (t + 2) << 6);
    __builtin_amdgcn_s_setprio(1);
#pragma unroll
    for (int mi = 0; mi < 2; ++mi)
#pragma unroll
      for (int ni = 0; ni < 2; ++ni)
        acc[mi][ni] = __builtin_amdgcn_mfma_f32_16x16x32_bf16(a1[mi], b1[ni], acc[mi][ni], 0, 0, 0);
    __builtin_amdgcn_s_setprio(0);
    if (t + 2 < nt) {
      asm volatile("s_waitcnt vmcnt(3)" ::: "memory");
    } else if (t + 1 < nt) {
      asm volatile("s_waitcnt vmcnt(0)" ::: "memory");
    }
    __builtin_amdgcn_sched_barrier(0);
    __builtin_amdgcn_s_barrier();
    cur ^= 1;
  }
#pragma unroll
  for (int mi = 0; mi < 2; ++mi) {
#pragma unroll
    for (int ni = 0; ni < 2; ++ni) {
      int row0 = m0 + wm * 32 + mi * 16 + g * 4;
      int col  = n0 + wn * 32 + ni * 16 + l15;
      float bcol = bias[col];
#pragma unroll
      for (int j = 0; j < 4; ++j) {
        size_t idx = (size_t)(row0 + j) * N + col;
        float rv = RESB ? b2f(residb[idx]) : residf[idx];
        float vv = acc[mi][ni][j] + bcol + rv;
        if (OUTB) outw[idx] = f2b(vv);
        else      outf[idx] = vv;
      }
    }
  }
}

// ---- flash attention: 1-D grid 512, XCD-clustered, KVBLK=128, both-halves ILP ----
__global__ __launch_bounds__(512) void k_attn(
    const unsigned short* __restrict__ qb, const unsigned short* __restrict__ kb,
    const unsigned short* __restrict__ vt, unsigned short* __restrict__ attn_out) {
  __shared__ __align__(16) unsigned short Ks[128][64];
  __shared__ __align__(16) unsigned short Vs[2][64][64];
  __shared__ __align__(16) unsigned short Plds[8][2][16][72];
  int id = blockIdx.x;
  int slot = id & 7, step = id >> 3;
  int bh = slot * 4 + (step >> 4);
  int qblk = step & 15;
  int b = bh >> 4, h = bh & 15;
  int tid = threadIdx.x;
  int lane = tid & 63, wid = tid >> 6;
  int l15 = lane & 15, g = lane >> 4;
  int q0 = qblk * 128 + wid * 16;
  const unsigned short* Qb = qb + (size_t)bh * 2048 * 64;
  const unsigned short* Kb = kb + (size_t)bh * 2048 * 64;
  const unsigned short* Vt = vt + (size_t)bh * 64 * 2048;
  short8 qf0 = *reinterpret_cast<const short8*>(&Qb[(size_t)(q0 + l15) * 64 + g * 8]);
  short8 qf1 = *reinterpret_cast<const short8*>(&Qb[(size_t)(q0 + l15) * 64 + 32 + g * 8]);
  short8 vones;
#pragma unroll
  for (int i = 0; i < 8; ++i) vones[i] = (short)0x3F80;
  float mj = 0.0f;
  f32x4 o[4] = {};
  f32x4 lacc = {};
  int kr  = wid * 16 + (lane >> 3);
  int kcn = (lane & 7) ^ (kr & 7);
  int vr  = wid * 8 + (lane >> 3);
  int vcn = (lane & 7) ^ (vr & 7);
  int swl = l15 & 7;
  for (int t0 = 0; t0 < 2048; t0 += 128) {
    __syncthreads();
    gl16(Kb + (size_t)(t0 + kr) * 64 + kcn * 8,      &Ks[wid * 16][0]);
    gl16(Kb + (size_t)(t0 + kr + 8) * 64 + kcn * 8,  &Ks[wid * 16 + 8][0]);
    gl16(Vt + (size_t)vr * 2048 + t0 + vcn * 8,      &Vs[0][wid * 8][0]);
    gl16(Vt + (size_t)vr * 2048 + t0 + 64 + vcn * 8, &Vs[1][wid * 8][0]);
    __syncthreads();
    f32x4 scv[2][4];
#pragma unroll
    for (int half = 0; half < 2; ++half)
#pragma unroll
      for (int kk = 0; kk < 4; ++kk) {
        short8 kf0 = *reinterpret_cast<const short8*>(&Ks[half * 64 + kk * 16 + l15][(g ^ swl) * 8]);
        short8 kf1 = *reinterpret_cast<const short8*>(&Ks[half * 64 + kk * 16 + l15][((4 + g) ^ swl) * 8]);
        f32x4 z = {};
        z = __builtin_amdgcn_mfma_f32_16x16x32_bf16(kf0, qf0, z, 0, 0, 0);
        scv[half][kk] = __builtin_amdgcn_mfma_f32_16x16x32_bf16(kf1, qf1, z, 0, 0, 0);
      }
    float p[2][16];
#pragma unroll
    for (int half = 0; half < 2; ++half)
#pragma unroll
      for (int kk = 0; kk < 4; ++kk)
#pragma unroll
        for (int j = 0; j < 4; ++j)
          p[half][kk * 4 + j] = __builtin_amdgcn_exp2f(scv[half][kk][j] - mj);
#pragma unroll
    for (int half = 0; half < 2; ++half)
#pragma unroll
      for (int kk = 0; kk < 4; ++kk) {
        unsigned r0, r1;
        asm("v_cvt_pk_bf16_f32 %0, %1, %2" : "=v"(r0) : "v"(p[half][kk * 4 + 0]), "v"(p[half][kk * 4 + 1]));
        asm("v_cvt_pk_bf16_f32 %0, %1, %2" : "=v"(r1) : "v"(p[half][kk * 4 + 2]), "v"(p[half][kk * 4 + 3]));
        unsigned long long w = (unsigned long long)r0 | ((unsigned long long)r1 << 32);
        *reinterpret_cast<unsigned long long*>(&Plds[wid][half][l15][kk * 16 + g * 4]) = w;
      }
    float mx = -1e30f;
#pragma unroll
    for (int half = 0; half < 2; ++half)
#pragma unroll
      for (int kk = 0; kk < 4; ++kk)
#pragma unroll
        for (int j = 0; j < 4; ++j) mx = fmaxf(mx, scv[half][kk][j]);
    mx = fmaxf(mx, __shfl_xor(mx, 16));
    mx = fmaxf(mx, __shfl_xor(mx, 32));
    if (!__all(mx <= mj + 8.0f)) {
      float mnew = fmaxf(mj, mx);
      float ef = __builtin_amdgcn_exp2f(mj - mnew);
      int sb = 20 * g;
      float e0 = __shfl(ef, sb + 0), e1 = __shfl(ef, sb + 1);
      float e2 = __shfl(ef, sb + 2), e3 = __shfl(ef, sb + 3);
#pragma unroll
      for (int ct = 0; ct < 4; ++ct) {
        o[ct][0] *= e0; o[ct][1] *= e1; o[ct][2] *= e2; o[ct][3] *= e3;
      }
      lacc[0] *= e0; lacc[1] *= e1; lacc[2] *= e2; lacc[3] *= e3;
#pragma unroll
      for (int half = 0; half < 2; ++half)
#pragma unroll
        for (int kk = 0; kk < 4; ++kk) {
#pragma unroll
          for (int j = 0; j < 4; ++j)
            p[half][kk * 4 + j] = __builtin_amdgcn_exp2f(scv[half][kk][j] - mnew);
          unsigned r0, r1;
          asm("v_cvt_pk_bf16_f32 %0, %1, %2" : "=v"(r0) : "v"(p[half][kk * 4 + 0]), "v"(p[half][kk * 4 + 1]));
          asm("v_cvt_pk_bf16_f32 %0, %1, %2" : "=v"(r1) : "v"(p[half][kk * 4 + 2]), "v"(p[half][kk * 4 + 3]));
          unsigned long long w = (unsigned long long)r0 | ((unsigned long long)r1 << 32);
          *reinterpret_cast<unsigned long long*>(&Plds[wid][half][l15][kk * 16 + g * 4]) = w;
        }
      mj = mnew;
    }
#pragma unroll
    for (int half = 0; half < 2; ++half) {
      short8 pf0 = *reinterpret_cast<const short8*>(&Plds[wid][half][l15][g * 8]);
      short8 pf1 = *reinterpret_cast<const short8*>(&Plds[wid][half][l15][32 + g * 8]);
      lacc = __builtin_amdgcn_mfma_f32_16x16x32_bf16(pf0, vones, lacc, 0, 0, 0);
      lacc = __builtin_amdgcn_mfma_f32_16x16x32_bf16(pf1, vones, lacc, 0, 0, 0);
#pragma unroll
      for (int ct = 0; ct < 4; ++ct) {
        short8 vf0 = *reinterpret_cast<const short8*>(&Vs[half][ct * 16 + l15][(g ^ swl) * 8]);
        short8 vf1 = *reinterpret_cast<const short8*>(&Vs[half][ct * 16 + l15][((4 + g) ^ swl) * 8]);
        o[ct] = __builtin_amdgcn_mfma_f32_16x16x32_bf16(pf0, vf0, o[ct], 0, 0, 0);
        o[ct] = __builtin_amdgcn_mfma_f32_16x16x32_bf16(pf1, vf1, o[ct], 0, 0, 0);
      }
    }
  }
#pragma unroll
  for (int j = 0; j < 4; ++j) {
    float iv = 1.0f / lacc[j];
    size_t t = (size_t)b * 2048 + (q0 + g * 4 + j);
#pragma unroll
    for (int ct = 0; ct < 4; ++ct)
      attn_out[t * 1024 + h * 64 + ct * 16 + l15] = f2b(o[ct][j] * iv);
  }
}

extern "C" void kernel_launch(void* const* d_in, const int* in_sizes, int n_in,
                              void* d_out, int out_size, void* d_ws, size_t ws_size,
                              hipStream_t stream) {
  (void)in_sizes; (void)n_in; (void)out_size; (void)ws_size;
  const float* x      = (const float*)d_in[0];
  const float* ln1_g  = (const float*)d_in[1];
  const float* ln1_b  = (const float*)d_in[2];
  const float* w_qkv  = (const float*)d_in[3];
  const float* b_qkv  = (const float*)d_in[4];
  const float* w_ao   = (const float*)d_in[5];
  const float* b_ao   = (const float*)d_in[6];
  const float* ln2_g  = (const float*)d_in[7];
  const float* ln2_b  = (const float*)d_in[8];
  const float* w_fc   = (const float*)d_in[9];
  const float* b_fc   = (const float*)d_in[10];
  const float* w_proj = (const float*)d_in[11];
  const float* b_proj = (const float*)d_in[12];
  float* out = (float*)d_out;

  char* ws = (char*)d_ws;
  size_t o = 0;
  auto nxt = [&](size_t bytes) { void* p = ws + o; o += (bytes + 255) & ~(size_t)255; return p; };
  unsigned short* wT_qkv  = (unsigned short*)nxt((size_t)3072 * 1024 * 2);
  unsigned short* wT_ao   = (unsigned short*)nxt((size_t)1024 * 1024 * 2);
  unsigned short* wT_fc   = (unsigned short*)nxt((size_t)4096 * 1024 * 2);
  unsigned short* wT_proj = (unsigned short*)nxt((size_t)1024 * 4096 * 2);
  unsigned short* h_ln    = (unsigned short*)nxt((size_t)4096 * 1024 * 2);
  unsigned short* qbuf    = (unsigned short*)nxt((size_t)4096 * 1024 * 2);
  unsigned short* kbuf    = (unsigned short*)nxt((size_t)4096 * 1024 * 2);
  unsigned short* vtb     = (unsigned short*)nxt((size_t)4096 * 1024 * 2);
  unsigned short* attn_o  = (unsigned short*)nxt((size_t)4096 * 1024 * 2);
  unsigned short* out1b   = (unsigned short*)nxt((size_t)4096 * 1024 * 2);
  unsigned short* fc_buf  = qbuf;  // reuse qkv region after attention

  dim3 b32(32, 8, 1);
  k_pre<<<16384, b32, 0, stream>>>(w_qkv, wT_qkv, w_ao, wT_ao, w_fc, wT_fc, w_proj, wT_proj,
                                   x, ln1_g, ln1_b, h_ln);
  k_gemm256<EPI_QKV><<<dim3(12, 16), 1024, 0, stream>>>(h_ln, wT_qkv, b_qkv, 4096, 3072, 1024,
                                                        nullptr, qbuf, kbuf, vtb);
  k_attn<<<512, 512, 0, stream>>>(qbuf, kbuf, vtb, attn_o);
  k_gemm512<0, 1><<<dim3(8, 64), 512, 0, stream>>>(attn_o, wT_ao, b_ao, 4096, 1024, 1024,
                                                   nullptr, out1b, x, nullptr);
  k_lnb<<<4096, 256, 0, stream>>>(out1b, ln2_g, ln2_b, h_ln);
  k_gemm256<EPI_GELU><<<dim3(16, 16), 1024, 0, stream>>>(h_ln, wT_fc, b_fc, 4096, 4096, 1024,
                                                         fc_buf, nullptr, nullptr, nullptr);
  k_gemm512<1, 0><<<dim3(8, 64), 512, 0, stream>>>(fc_buf, wT_proj, b_proj, 4096, 1024, 4096,
                                                   out, nullptr, nullptr, out1b);
}